// Round 6
// baseline (2185.312 us; speedup 1.0000x reference)
//
#include <hip/hip_runtime.h>
#include <cstdint>
#include <cstddef>

// Problem constants
#define R_DIM   128
#define R2_DIM  64
#define MIX     32
#define IN_DIM  512
#define HID     256
#define B_SZ    256
#define T_SZ    16
#define MAX_IT  12

// Workspace layout (float offsets)
#define OFF_G    0           // 16384 (row-major 128x128)
#define OFF_U    16384       // 4096*128
#define OFF_SX   540672      // 4096

__device__ __forceinline__ float softt(float v, float lam) {
  float a = fabsf(v) - lam;
  return a > 0.f ? (v > 0.f ? a : -a) : 0.f;
}

__device__ __forceinline__ float rdlane(float v, int lane) {
  int i = __builtin_amdgcn_readlane(__float_as_int(v), lane);
  return __int_as_float(i);
}

__device__ __forceinline__ float wsum_all(float v) {
#pragma unroll
  for (int off = 32; off; off >>= 1) v += __shfl_xor(v, off, 64);
  return v;
}

__device__ __forceinline__ float wsum(float v) {  // result on lane 0
#pragma unroll
  for (int off = 32; off; off >>= 1) v += __shfl_down(v, off, 64);
  return v;
}

// ---------------- fused prep: G, U, SX, and zero the 3 loss slots -------------
// blocks 0..127   : G row i = blockIdx.x  (G = dec_W @ dec_W^T, 128x128)
// blocks 128..383 : U/SX for 16 (b,t) rows each
__global__ __launch_bounds__(128) void k_prep(const float* __restrict__ X,
                                              const float* __restrict__ decb,
                                              const float* __restrict__ decW,
                                              float* __restrict__ ws,
                                              float* __restrict__ out) {
  __shared__ __align__(16) float xm[16][IN_DIM];
  __shared__ float scr[128];
  float* G = ws + OFF_G;
  float* U = ws + OFF_U;
  float* SX = ws + OFF_SX;

  if (blockIdx.x < 128) {
    if (blockIdx.x == 0 && threadIdx.x < 3) out[threadIdx.x] = 0.f;  // loss acc
    int i = blockIdx.x;
    for (int d = threadIdx.x; d < IN_DIM; d += 128) xm[0][d] = decW[i * IN_DIM + d];
    __syncthreads();
    int j = threadIdx.x;
    const float* wr = decW + (size_t)j * IN_DIM;
    float acc = 0.f;
    for (int d4 = 0; d4 < IN_DIM / 4; d4++) {
      float4 w4 = *reinterpret_cast<const float4*>(wr + d4 * 4);
      float4 r4 = *reinterpret_cast<const float4*>(&xm[0][d4 * 4]);
      acc += w4.x * r4.x + w4.y * r4.y + w4.z * r4.z + w4.w * r4.w;
    }
    G[i * R_DIM + j] = acc;
    return;
  }

  int blk0 = (blockIdx.x - 128) * 16;
  for (int p = threadIdx.x; p < 16 * IN_DIM / 4; p += 128) {
    int g = p >> 7, c4 = p & 127;
    float4 xv = *reinterpret_cast<const float4*>(X + (size_t)(blk0 + g) * IN_DIM + c4 * 4);
    float4 bv = *reinterpret_cast<const float4*>(decb + c4 * 4);
    xm[g][c4 * 4 + 0] = xv.x - bv.x;
    xm[g][c4 * 4 + 1] = xv.y - bv.y;
    xm[g][c4 * 4 + 2] = xv.z - bv.z;
    xm[g][c4 * 4 + 3] = xv.w - bv.w;
  }
  __syncthreads();
  {  // sx: 8 threads/row, 64 elems each
    int g = threadIdx.x >> 3, q = threadIdx.x & 7;
    float s = 0.f;
    for (int dd = 0; dd < 64; dd++) { float v = xm[g][q * 64 + dd]; s += v * v; }
    scr[threadIdx.x] = s;
  }
  __syncthreads();
  if (threadIdx.x < 16) {
    float s = 0.f;
#pragma unroll
    for (int h = 0; h < 8; h++) s += scr[threadIdx.x * 8 + h];
    SX[blk0 + threadIdx.x] = s;
  }
  int i = threadIdx.x;
  const float* wr = decW + (size_t)i * IN_DIM;
  float acc[16];
#pragma unroll
  for (int g = 0; g < 16; g++) acc[g] = 0.f;
  for (int d4 = 0; d4 < IN_DIM / 4; d4++) {
    float4 w4 = *reinterpret_cast<const float4*>(wr + d4 * 4);
#pragma unroll
    for (int g = 0; g < 16; g++) {
      float4 xv = *reinterpret_cast<const float4*>(&xm[g][d4 * 4]);
      acc[g] += w4.x * xv.x + w4.y * xv.y + w4.z * xv.z + w4.w * xv.w;
    }
  }
  for (int g = 0; g < 16; g++) U[(size_t)(blk0 + g) * R_DIM + i] = acc[g];
}

// ---------------- persistent main kernel: one wave per batch element ----------
// G columns l / l+64, pre-scaled by 0.2: Ga[128] in arch VGPRs, Gb[128] pinned
// to AGPRs via v_accvgpr inline asm (unified 512-reg file; arch encoding caps
// at 256 -> without this the allocator spills to scratch, R5's 14.5 MB WRITE).
__global__ __launch_bounds__(64, 1) void k_main(
    float* __restrict__ ws, const float* __restrict__ T2,
    const float* __restrict__ h1W, const float* __restrict__ h1b,
    const float* __restrict__ lns, const float* __restrict__ lnb,
    const float* __restrict__ h2W, const float* __restrict__ h2b,
    const float* __restrict__ h3W, const float* __restrict__ h3b,
    float* __restrict__ out) {
  __shared__ __align__(16) float cS[MIX * 129];
  __shared__ __align__(16) float aL[HID];
  __shared__ __align__(16) float x2L[HID];
  __shared__ __align__(16) float dx1L[HID];
  __shared__ __align__(16) float dx2L[HID];
  __shared__ __align__(16) float wL[MIX];
  __shared__ __align__(16) float dx3L[MIX];
  __shared__ __align__(16) float eL[R_DIM];
  __shared__ __align__(16) float rpL[R_DIM];

  const int l = threadIdx.x;
  const int b = blockIdx.x;
  const float* Gg = ws + OFF_G;
  const float* Ug = ws + OFF_U;
  const float* SXg = ws + OFF_SX;

  // Stage scaled G: Ga -> arch VGPRs, Gb -> AGPRs.
  float Ga[128];
  float GbA[128];
#pragma unroll
  for (int j = 0; j < 128; j++) {
    Ga[j] = 0.2f * Gg[j * R_DIM + l];
    float v = 0.2f * Gg[j * R_DIM + 64 + l];
    __asm__("v_accvgpr_write_b32 %0, %1" : "=a"(GbA[j]) : "v"(v));
  }

  float r0 = 0.f, r1 = 0.f, r2v = 0.f;
  bool zr2 = true, fwdv = false, zw = true, rhv = false, cst = false;
  float xh[4] = {0.f, 0.f, 0.f, 0.f}, av[4] = {0.f, 0.f, 0.f, 0.f}, rstd = 0.f;
  float rh0 = 0.f, rh1 = 0.f;
  float lc0 = 0.f, lc1 = 0.f, lc2 = 0.f, sxa = 0.f;

  // g_sc = 0.2 * (G r): per j = readlane + fmac(Ga) + accvgpr_read + fmac
  auto matvec = [&](float& g0, float& g1, float a0, float a1) {
    float p0[4] = {0.f, 0.f, 0.f, 0.f}, p1[4] = {0.f, 0.f, 0.f, 0.f};
#pragma unroll
    for (int j = 0; j < 128; j++) {
      float rj = rdlane((j < 64) ? a0 : a1, j & 63);
      float gb;
      __asm__("v_accvgpr_read_b32 %0, %1" : "=v"(gb) : "a"(GbA[j]));
      p0[j & 3] += rj * Ga[j];
      p1[j & 3] += rj * gb;
    }
    g0 = (p0[0] + p0[1]) + (p0[2] + p0[3]);
    g1 = (p1[0] + p1[1]) + (p1[2] + p1[3]);
  };

  // ---- cold hypernet machinery (LDS-based; only runs when w or r2 nonzero) --
  auto ensure_c = [&]() {
    if (cst) return;
    for (int p = l; p < MIX * R_DIM; p += 64) {
      const float* row = T2 + (size_t)p * R_DIM;
      float acc = 0.f;
      for (int j4 = 0; j4 < R_DIM / 4; j4++) {
        float4 w4 = *(const float4*)(row + j4 * 4);
        float4 r4 = *(const float4*)(&rpL[j4 * 4]);
        acc += w4.x * r4.x + w4.y * r4.y + w4.z * r4.z + w4.w * r4.w;
      }
      cS[(p >> 7) * 129 + (p & 127)] = acc;
    }
    cst = true;
  };

  auto rhat_comp = [&]() {
    float a0 = 0.f, a1 = 0.f;
#pragma unroll
    for (int m4 = 0; m4 < 8; m4++) {
      float4 w4 = *(const float4*)&wL[m4 * 4];
      int mb = m4 * 4;
      a0 += w4.x * cS[(mb + 0) * 129 + l] + w4.y * cS[(mb + 1) * 129 + l] +
            w4.z * cS[(mb + 2) * 129 + l] + w4.w * cS[(mb + 3) * 129 + l];
      a1 += w4.x * cS[(mb + 0) * 129 + 64 + l] + w4.y * cS[(mb + 1) * 129 + 64 + l] +
            w4.z * cS[(mb + 2) * 129 + 64 + l] + w4.w * cS[(mb + 3) * 129 + 64 + l];
    }
    rh0 = a0; rh1 = a1;
  };

  auto hyp_fwd = [&]() {
    float x1[4];
#pragma unroll
    for (int q = 0; q < 4; q++) x1[q] = h1b[l + 64 * q];
    if (!zr2) {
      for (int k = 0; k < R2_DIM; k++) {
        float rk = rdlane(r2v, k);
        if (rk != 0.f) {
#pragma unroll
          for (int q = 0; q < 4; q++) x1[q] += rk * h1W[k * HID + l + 64 * q];
        }
      }
    }
    float s1 = x1[0] + x1[1] + x1[2] + x1[3];
    float s2 = x1[0] * x1[0] + x1[1] * x1[1] + x1[2] * x1[2] + x1[3] * x1[3];
    s1 = wsum_all(s1); s2 = wsum_all(s2);
    float mu = s1 * (1.f / HID);
    float var = s2 * (1.f / HID) - mu * mu;
    rstd = rsqrtf(var + 1e-6f);
    bool anz = false;
#pragma unroll
    for (int q = 0; q < 4; q++) {
      xh[q] = (x1[q] - mu) * rstd;
      float y = xh[q] * lns[l + 64 * q] + lnb[l + 64 * q];
      av[q] = (y > 0.f) ? y : expm1f(y);
      aL[l + 64 * q] = av[q];
      anz |= (av[q] != 0.f);
    }
    bool za = (__ballot(anz) == 0ull);
    float x2[4];
#pragma unroll
    for (int q = 0; q < 4; q++) x2[q] = h2b[l + 64 * q];
    if (!za) {
      for (int k4 = 0; k4 < HID / 4; k4++) {
        float4 a4 = *(const float4*)&aL[k4 * 4];
#pragma unroll
        for (int c = 0; c < 4; c++) {
          float ac = (&a4.x)[c];
          int k = k4 * 4 + c;
#pragma unroll
          for (int q = 0; q < 4; q++) x2[q] += ac * h2W[(size_t)k * HID + l + 64 * q];
        }
      }
    }
    bool x2nz = false;
#pragma unroll
    for (int q = 0; q < 4; q++) { x2L[l + 64 * q] = x2[q]; x2nz |= (x2[q] != 0.f); }
    bool zx2 = (__ballot(x2nz) == 0ull);
    int m = l & 31, kh = l >> 5;
    float p = 0.f;
    if (!zx2) {
      for (int kk = 0; kk < 128; kk++) {
        int k = kh * 128 + kk;
        p += x2L[k] * h3W[k * MIX + m];
      }
    }
    p += __shfl_xor(p, 32, 64);
    float wv = 0.f;
    if (l < 32) { wv = fmaxf(h3b[l] + p, 0.f); wL[l] = wv; }
    zw = (__ballot(wv != 0.f) == 0ull);
  };

  auto hyp_bwd = [&]() -> bool {  // returns "r2 changed"
    bool zd3 = true;
    if (!zw) {
      ensure_c();
      int m = l & 31, ih = l >> 5;
      float p = 0.f;
      for (int ii = 0; ii < 64; ii++) {
        int i = ih * 64 + ii;
        p += eL[i] * cS[m * 129 + i];
      }
      p += __shfl_xor(p, 32, 64);
      float d3 = 0.f;
      if (l < 32) { d3 = (wL[l] > 0.f) ? (-2.f * p) : 0.f; dx3L[l] = d3; }
      zd3 = (__ballot(d3 != 0.f) == 0ull);
    }
    float g = 0.f;
    if (!zd3) {
      float dx2[4] = {0.f, 0.f, 0.f, 0.f};
#pragma unroll
      for (int m4 = 0; m4 < 8; m4++) {
        float4 d4 = *(const float4*)&dx3L[m4 * 4];
#pragma unroll
        for (int q = 0; q < 4; q++) {
          const float* r3 = h3W + (size_t)(l + 64 * q) * MIX + m4 * 4;
          dx2[q] += d4.x * r3[0] + d4.y * r3[1] + d4.z * r3[2] + d4.w * r3[3];
        }
      }
#pragma unroll
      for (int q = 0; q < 4; q++) dx2L[l + 64 * q] = dx2[q];
      float dxh[4];
      float s1 = 0.f, s2 = 0.f;
#pragma unroll
      for (int q = 0; q < 4; q++) {
        float da = 0.f;
        const float* row = h2W + (size_t)(l + 64 * q) * HID;
        for (int k4 = 0; k4 < HID / 4; k4++) {
          float4 w4 = *(const float4*)(row + k4 * 4);
          float4 d4 = *(const float4*)&dx2L[k4 * 4];
          da += w4.x * d4.x + w4.y * d4.y + w4.z * d4.z + w4.w * d4.w;
        }
        float dy = da * (av[q] > 0.f ? 1.f : (av[q] + 1.f));
        dxh[q] = dy * lns[l + 64 * q];
        s1 += dxh[q]; s2 += dxh[q] * xh[q];
      }
      s1 = wsum_all(s1); s2 = wsum_all(s2);
#pragma unroll
      for (int q = 0; q < 4; q++) {
        float dx1 = rstd * (dxh[q] - s1 * (1.f / HID) - xh[q] * (s2 * (1.f / HID)));
        dx1L[l + 64 * q] = dx1;
      }
      const float* row1 = h1W + (size_t)l * HID;
      for (int j4 = 0; j4 < HID / 4; j4++) {
        float4 w4 = *(const float4*)(row1 + j4 * 4);
        float4 d4 = *(const float4*)&dx1L[j4 * 4];
        g += w4.x * d4.x + w4.y * d4.y + w4.z * d4.z + w4.w * d4.w;
      }
    }
    float r2n = softt(r2v - 0.1f * g, 0.001f);
    bool ch = (__ballot(r2n != r2v) != 0ull);
    r2v = r2n;
    zr2 = (__ballot(r2n != 0.f) == 0ull);
    return ch;
  };

  // prefetch step 0
  float u0n = Ug[(size_t)(b * T_SZ) * R_DIM + l];
  float u1n = Ug[(size_t)(b * T_SZ) * R_DIM + 64 + l];
  float sxn = SXg[b * T_SZ];

#pragma unroll 1
  for (int t = 0; t < T_SZ; t++) {
    float u0 = u0n, u1 = u1n, sxv = sxn;
    if (t < T_SZ - 1) {
      u0n = Ug[(size_t)(b * T_SZ + t + 1) * R_DIM + l];
      u1n = Ug[(size_t)(b * T_SZ + t + 1) * R_DIM + 64 + l];
      sxn = SXg[b * T_SZ + t + 1];
    }
    float u02_0 = 0.2f * u0, u02_1 = 0.2f * u1;
    rpL[l] = r0; rpL[64 + l] = r1;  // r_prev for c
    cst = false; rhv = false;
    if (!fwdv) { hyp_fwd(); fwdv = true; }
    if (zw) { rh0 = 0.f; rh1 = 0.f; } else { ensure_c(); rhat_comp(); }
    rhv = true;
    // warm start r0 = temp_pred (no threshold)
    r0 = rh0; r1 = rh1;
    bool rzero = zw;
#pragma unroll 1
    for (int it = 0; it < MAX_IT; it++) {
      if (!rhv) {
        if (zw) { rh0 = 0.f; rh1 = 0.f; } else { ensure_c(); rhat_comp(); }
        rhv = true;
      }
      float e0 = r0 - rh0, e1 = r1 - rh1;
      float g0 = 0.f, g1 = 0.f;
      if (!rzero) matvec(g0, g1, r0, r1);
      rzero = false;
      // r <- softt(r - 0.2*(G r) - 0.2*e + 0.2*u, 0.001); g already scaled
      r0 = softt(r0 - g0 - 0.2f * e0 + u02_0, 0.001f);
      r1 = softt(r1 - g1 - 0.2f * e1 + u02_1, 0.001f);
      if (!(zw && zr2)) {  // else r2 provably unchanged (all-zero fixed point)
        eL[l] = e0; eL[64 + l] = e1;
        bool ch = hyp_bwd();
        if (ch) fwdv = false;
        if (!fwdv) { hyp_fwd(); fwdv = true; rhv = false; }
      }
    }
    // epilogue losses (quadratic form; matvec returns 0.2*G v -> rescale by 5)
    if (!rhv) {
      if (zw) { rh0 = 0.f; rh1 = 0.f; } else { ensure_c(); rhat_comp(); }
      rhv = true;
    }
    float gb0, gb1;
    matvec(gb0, gb1, r0, r1);
    lc1 += r0 * (5.f * gb0) - 2.f * r0 * u0 + r1 * (5.f * gb1) - 2.f * r1 * u1;
    if (zw) {
      lc2 += r0 * r0 + r1 * r1;  // rhat = 0; c0 contribution = 0
    } else {
      float gh0, gh1;
      matvec(gh0, gh1, rh0, rh1);
      lc0 += rh0 * (5.f * gh0) - 2.f * rh0 * u0 + rh1 * (5.f * gh1) - 2.f * rh1 * u1;
      float d0 = r0 - rh0, d1 = r1 - rh1;
      lc2 += d0 * d0 + d1 * d1;
    }
    if (l == 0) sxa += sxv;
  }

  const float inv = 1.f / (B_SZ * T_SZ);
  float t0 = wsum(lc0), t1 = wsum(lc1), t2 = wsum(lc2);
  if (l == 0) {
    atomicAdd(&out[0], (t0 + sxa) * inv);
    atomicAdd(&out[1], (t1 + sxa) * inv);
    atomicAdd(&out[2], t2 * inv);
  }
  out[3 + b * R_DIM + l] = r0;
  out[3 + b * R_DIM + 64 + l] = r1;
  out[3 + B_SZ * R_DIM + b * R2_DIM + l] = r2v;
}

extern "C" void kernel_launch(void* const* d_in, const int* in_sizes, int n_in,
                              void* d_out, int out_size, void* d_ws, size_t ws_size,
                              hipStream_t stream) {
  const float* X = (const float*)d_in[0];
  const float* decW = (const float*)d_in[1];
  const float* decb = (const float*)d_in[2];
  const float* temporal = (const float*)d_in[3];
  const float* h1W = (const float*)d_in[4];
  const float* h1b = (const float*)d_in[5];
  const float* lns = (const float*)d_in[6];
  const float* lnb = (const float*)d_in[7];
  const float* h2W = (const float*)d_in[8];
  const float* h2b = (const float*)d_in[9];
  const float* h3W = (const float*)d_in[10];
  const float* h3b = (const float*)d_in[11];
  float* ws = (float*)d_ws;  // ~2.1 MiB used
  float* out = (float*)d_out;

  k_prep<<<384, 128, 0, stream>>>(X, decb, decW, ws, out);
  k_main<<<B_SZ, 64, 0, stream>>>(ws, temporal, h1W, h1b, lns, lnb,
                                  h2W, h2b, h3W, h3b, out);
}